// Round 5
// baseline (155.176 us; speedup 1.0000x reference)
//
#include <hip/hip_runtime.h>
#include <math.h>

#define C_DIM 1000
#define VEC4  250
#define WAVES_PER_BLOCK 4
#define ROWS_PER_WAVE 2     // sequential rows per wave (software pipeline)
#define BIG 1.0e30f         // pad: u^5 -> inf -> rcp = 0 -> self-masking

__device__ __forceinline__ float fast_exp2(float x) { return __builtin_amdgcn_exp2f(x); }
__device__ __forceinline__ float fast_log2(float x) { return __builtin_amdgcn_logf(x); }

__device__ __forceinline__ float reduce1(float a) {
    #pragma unroll
    for (int off = 32; off > 0; off >>= 1) a += __shfl_xor(a, off, 64);
    return a;
}
__device__ __forceinline__ void reduce2(float& a, float& b) {
    #pragma unroll
    for (int off = 32; off > 0; off >>= 1) {
        a += __shfl_xor(a, off, 64);
        b += __shfl_xor(b, off, 64);
    }
}
__device__ __forceinline__ void reduce3(float& a, float& b, float& c) {
    #pragma unroll
    for (int off = 32; off > 0; off >>= 1) {
        a += __shfl_xor(a, off, 64);
        b += __shfl_xor(b, off, 64);
        c += __shfl_xor(c, off, 64);
    }
}
__device__ __forceinline__ float reduce_max(float a) {
    #pragma unroll
    for (int off = 32; off > 0; off >>= 1) a = fmaxf(a, __shfl_xor(a, off, 64));
    return a;
}
__device__ __forceinline__ double reduce_d(double v) {
    #pragma unroll
    for (int off = 32; off > 0; off >>= 1) v += __shfl_xor(v, off, 64);
    return v;
}

// Solve sum (w+b)^-5 = 1 for w: 2 tempered-softmax fixed-point sweeps
// (contraction ~0.16) then 2 Newton sweeps (monotone-safe from below on the
// convex decreasing g). Converges to fp32 round-off (absmax 0.0 in R3/R4).
__device__ __forceinline__ float solve_w(const float b[16]) {
    float s = 0.0f;
    #pragma unroll
    for (int k = 0; k < 16; ++k) {
        float u  = 1.0f + b[k];
        float u2 = u * u;
        float u4 = u2 * u2;
        s += __builtin_amdgcn_rcpf(u4 * u);
    }
    s = reduce1(s);
    const float lam = fast_exp2(-0.2f * fast_log2(s));

    s = 0.0f;
    #pragma unroll
    for (int k = 0; k < 16; ++k) {
        float u  = fmaf(lam, b[k], 1.0f);
        float u2 = u * u;
        float u4 = u2 * u2;
        s += __builtin_amdgcn_rcpf(u4 * u);
    }
    s = reduce1(s);
    float w = fast_exp2(0.2f * fast_log2(s));   // below root -> Newton safe

    #pragma unroll
    for (int it = 0; it < 2; ++it) {
        float s0 = 0.0f, s1 = 0.0f;
        #pragma unroll
        for (int k = 0; k < 16; ++k) {
            float u  = w + b[k];
            float r  = __builtin_amdgcn_rcpf(u);
            float r2 = r * r;
            float r4 = r2 * r2;
            float r5 = r4 * r;
            s0 += r5;
            s1 += r5 * r;
        }
        reduce2(s0, s1);
        w = fmaf((s0 - 1.0f) * 0.2f, __builtin_amdgcn_rcpf(s1), w);
    }
    return w;
}

// Row loss = C0 - E_off*S4 - dE*r4_hot + (1/1.8)*S9   (one-hot targets)
__device__ __forceinline__ float row_loss(const float b[16], float w, unsigned mask,
                                          float C0, float E_off, float dE) {
    float S4 = 0.0f, S9 = 0.0f, H = 0.0f;
    #pragma unroll
    for (int k = 0; k < 16; ++k) {
        float u  = w + b[k];
        float r  = __builtin_amdgcn_rcpf(u);
        float r2 = r * r;
        float r4 = r2 * r2;
        float r8 = r4 * r4;
        float r9 = r8 * r;
        S4 += r4;
        S9 += r9;
        float bitf = (float)((mask >> k) & 1u);
        H = fmaf(bitf, r4, H);
    }
    reduce3(S4, S9, H);
    return fmaf(-E_off, S4, fmaf(1.0f / 1.8f, S9, fmaf(-dE, H, C0)));
}

__device__ __forceinline__ void make_b(const float4 x[4], float b[16]) {
    float t[16];
    t[0]=x[0].x; t[1]=x[0].y; t[2]=x[0].z; t[3]=x[0].w;
    t[4]=x[1].x; t[5]=x[1].y; t[6]=x[1].z; t[7]=x[1].w;
    t[8]=x[2].x; t[9]=x[2].y; t[10]=x[2].z; t[11]=x[2].w;
    t[12]=x[3].x; t[13]=x[3].y; t[14]=x[3].z; t[15]=x[3].w;
    float mu = -3.4e38f;
    #pragma unroll
    for (int k = 0; k < 16; ++k) mu = fmaxf(mu, t[k]);
    mu = reduce_max(mu);
    #pragma unroll
    for (int k = 0; k < 16; ++k) b[k] = -0.2f * (t[k] - mu);  // pad -> ~2e29
}

__device__ __forceinline__ unsigned make_mask(const float4 t[4]) {
    unsigned m = 0;
    #pragma unroll
    for (int j = 0; j < 4; ++j) {
        m |= (t[j].x != 0.0f ? 1u : 0u) << (4 * j + 0);
        m |= (t[j].y != 0.0f ? 1u : 0u) << (4 * j + 1);
        m |= (t[j].z != 0.0f ? 1u : 0u) << (4 * j + 2);
        m |= (t[j].w != 0.0f ? 1u : 0u) << (4 * j + 3);
    }
    return m;
}

__global__ __launch_bounds__(256) void btll_rows(
    const float* __restrict__ inputs, const float* __restrict__ targets,
    float* __restrict__ row_out, int n_rows,
    float C0, float E_off, float dE)
{
    const int lane = threadIdx.x & 63;
    const int wave = threadIdx.x >> 6;
    const int gid  = blockIdx.x * WAVES_PER_BLOCK + wave;
    const int rA   = gid * ROWS_PER_WAVE;
    if (rA >= n_rows) return;
    const int rB   = (rA + 1 < n_rows) ? rA + 1 : rA;

    const float4* inA = (const float4*)(inputs  + (size_t)rA * C_DIM);
    const float4* tgA = (const float4*)(targets + (size_t)rA * C_DIM);
    const float4* inB = (const float4*)(inputs  + (size_t)rB * C_DIM);
    const float4* tgB = (const float4*)(targets + (size_t)rB * C_DIM);

    bool vm[4];
    int idx4[4];
    #pragma unroll
    for (int j = 0; j < 4; ++j) { idx4[j] = lane + 64 * j; vm[j] = idx4[j] < VEC4; }

    const float4 padA = make_float4(-BIG, -BIG, -BIG, -BIG);
    const float4 zero = make_float4(0.f, 0.f, 0.f, 0.f);

    // ---- issue A inputs, A targets, B inputs (B covered by A's solve) ----
    float4 xa[4], ta[4], xb[4];
    #pragma unroll
    for (int j = 0; j < 4; ++j) xa[j] = vm[j] ? inA[idx4[j]] : padA;
    #pragma unroll
    for (int j = 0; j < 4; ++j) ta[j] = vm[j] ? tgA[idx4[j]] : zero;
    #pragma unroll
    for (int j = 0; j < 4; ++j) xb[j] = vm[j] ? inB[idx4[j]] : padA;

    float bA[16];
    make_b(xa, bA);                 // waits xa (ta, xb still in flight)
    const unsigned mA = make_mask(ta);

    const float wA = solve_w(bA);   // ~5 sweeps; xb streams underneath

    float bB[16];
    make_b(xb, bB);

    // ---- issue B targets; covered by A epilogue ----
    float4 tb[4];
    #pragma unroll
    for (int j = 0; j < 4; ++j) tb[j] = vm[j] ? tgB[idx4[j]] : zero;

    const float lossA = row_loss(bA, wA, mA, C0, E_off, dE);

    const float wB = solve_w(bB);
    const unsigned mB = make_mask(tb);
    const float lossB = row_loss(bB, wB, mB, C0, E_off, dE);

    if (lane == 0) {
        row_out[rA] = lossA;
        if (rB != rA) row_out[rB] = lossB;
    }
}

__global__ __launch_bounds__(1024) void reduce_mean(
    const float* __restrict__ row_out, float* __restrict__ out, int n)
{
    __shared__ double sm[16];
    const int lane = threadIdx.x & 63;
    const int wv   = threadIdx.x >> 6;
    double s = 0.0;
    for (int i = threadIdx.x; i < n; i += 1024) s += (double)row_out[i];
    s = reduce_d(s);
    if (lane == 0) sm[wv] = s;
    __syncthreads();
    if (wv == 0) {
        double t = (lane < 16) ? sm[lane] : 0.0;
        t = reduce_d(t);
        if (lane == 0) out[0] = (float)(t / (double)n);
    }
}

extern "C" void kernel_launch(void* const* d_in, const int* in_sizes, int n_in,
                              void* d_out, int out_size, void* d_ws, size_t ws_size,
                              hipStream_t stream) {
    const float* inputs  = (const float*)d_in[0];
    const float* targets = (const float*)d_in[1];
    float* out = (float*)d_out;

    const int N = in_sizes[0] / C_DIM;
    float* row_out = (float*)d_ws;

    // Per-elem loss = F - E*r4 + r9/1.8 with two-valued smoothed targets.
    // Row sum = C0 - E_off*S4 - (E_on-E_off)*r4_hot + S9/1.8,
    // C0 = (C-1)*F_off + F_on.
    const double ls    = 0.05;
    const double c1g_d = 1.0 - (1000.0 / 999.0) * ls;
    const double c2_d  = ls / 999.0;
    const float  tp_on_f  = (float)c1g_d + (float)c2_d;
    const float  tp_off_f = (float)c2_d;
    const double tp_on  = (double)tp_on_f;
    const double tp_off = (double)tp_off_f;
    const double A_on  = (pow(tp_on  + 1e-8, 0.8) - 1.0) / 0.8;
    const double A_off = (pow(tp_off + 1e-8, 0.8) - 1.0) / 0.8;
    const double B_on  = pow(tp_on,  1.8);
    const double B_off = pow(tp_off, 1.8);
    const double E_on_d  = 1.25 * tp_on;
    const double E_off_d = 1.25 * tp_off;
    const double F_on_d  = tp_on  * A_on  + E_on_d  - B_on  / 1.8;
    const double F_off_d = tp_off * A_off + E_off_d - B_off / 1.8;
    const double C0_d    = (C_DIM - 1) * F_off_d + F_on_d;
    const double dE_d    = E_on_d - E_off_d;

    const int rows_per_block = WAVES_PER_BLOCK * ROWS_PER_WAVE;
    dim3 grid((N + rows_per_block - 1) / rows_per_block);
    btll_rows<<<grid, 256, 0, stream>>>(inputs, targets, row_out, N,
                                        (float)C0_d, (float)E_off_d, (float)dE_d);
    reduce_mean<<<1, 1024, 0, stream>>>(row_out, out, N);
}